// Round 5
// baseline (492.199 us; speedup 1.0000x reference)
//
#include <hip/hip_runtime.h>

#define NB 2
#define CCH 64
#define LL 8
#define HH 160
#define WW 160
#define PP 8
#define NPH 20
#define NPW 20
#define NPAT (NB*NPH*NPW)      // 800
#define NE 8
#define HWX (HH*WW)            // 25600
#define CSTRIDE (LL*HWX)       // 204800

typedef float f32x4  __attribute__((ext_vector_type(4)));
typedef float f32x16 __attribute__((ext_vector_type(16)));
typedef short bf16x8 __attribute__((ext_vector_type(8)));

__device__ __host__ __forceinline__ unsigned short f2bf(float f) {
    unsigned u = __builtin_bit_cast(unsigned, f);
    u = (u + 0x7FFFu + ((u >> 16) & 1u)) >> 16;
    return (unsigned short)u;
}
template<int CTRL>
__device__ __forceinline__ float dpp0(float v) {   // old=0, bound_ctrl=true
    return __builtin_bit_cast(float, __builtin_amdgcn_update_dpp(
        0, __builtin_bit_cast(int, v), CTRL, 0xF, 0xF, true));
}
__device__ __forceinline__ float dpp_xor1(float v) {  // quad_perm [1,0,3,2]
    int s = __builtin_bit_cast(int, v);
    return __builtin_bit_cast(float, __builtin_amdgcn_update_dpp(s, s, 0xB1, 0xF, 0xF, false));
}
__device__ __forceinline__ float wsum64(float v) {
    v += dpp0<0x111>(v); v += dpp0<0x112>(v); v += dpp0<0x114>(v);
    v += dpp0<0x118>(v); v += dpp0<0x142>(v); v += dpp0<0x143>(v);
    return __builtin_bit_cast(float, __builtin_amdgcn_readlane(__builtin_bit_cast(int, v), 63));
}
__device__ __forceinline__ float bperm(int a4, float v) {
    return __builtin_bit_cast(float, __builtin_amdgcn_ds_bpermute(a4, __builtin_bit_cast(int, v)));
}

// ---------------- Prep ----------------
__global__ __launch_bounds__(256)
void prep_kernel(const float* __restrict__ pwin_w, const float* __restrict__ pwout_w,
                 const float* __restrict__ dw_w,
                 unsigned short* __restrict__ w1t, unsigned short* __restrict__ w2t,
                 float* __restrict__ w1sum, unsigned short* __restrict__ mx, int full)
{
    int idx = blockIdx.x * 256 + threadIdx.x;
    if (full) {
        int j = idx & 7, lane = (idx >> 3) & 63, ks = (idx >> 9) & 1;
        int mt = (idx >> 10) & 3, c = (idx >> 12) & 63, e = idx >> 18;
        int m = 16*mt + (lane & 15);
        int k = ks*32 + ((lane >> 4) << 3) + j;
        int di = (k >> 3) - (m >> 3) + 3;
        int dj = (k & 7) - (m & 7) + 3;
        float v = 0.f;
        if (di >= 0 && di < 7 && dj >= 0 && dj < 7)
            v = dw_w[(e*CCH + c)*49 + di*7 + dj];
        mx[idx] = f2bf(v);
        if (idx < NE*128) {
            int e2 = idx >> 7, dp = idx & 127;
            int orig = (dp & 1) ? 64 + (dp >> 1) : (dp >> 1);
            float s = 0.f;
            for (int cc = 0; cc < 64; ++cc) s += pwin_w[(e2 << 13) + orig*64 + cc];
            w1sum[idx] = s;
        }
    }
    if (idx < NE*128*64) {
        int e = idx >> 13, r = (idx >> 6) & 127, c = idx & 63;
        int orig = (r & 1) ? 64 + (r >> 1) : (r >> 1);
        w1t[idx] = f2bf(pwin_w[(e << 13) + orig*64 + c]);
    }
    if (idx < NE*64*64) w2t[idx] = f2bf(pwout_w[idx]);
}

// ---------------- Router ----------------
__global__ __launch_bounds__(256)
void router_kernel(const float* __restrict__ x,
                   const float* __restrict__ rw,
                   const float* __restrict__ rb,
                   int* __restrict__ sel_idx,
                   float* __restrict__ sel_w)
{
    int n = blockIdx.x;
    int b = n / (NPH*NPW);
    int rem = n - b*(NPH*NPW);
    int ph = rem / NPW, pw = rem - ph*NPW;
    int t = threadIdx.x;
    int c = t >> 2, part = t & 3;

    const float* xl0 = x + ((size_t)(b*CCH + c)*LL)*HWX + (size_t)(ph*PP)*WW + pw*PP;
    float s = 0.f;
    for (int l = part*2; l < part*2 + 2; ++l) {
        const float* xl = xl0 + (size_t)l*HWX;
        #pragma unroll
        for (int i = 0; i < 8; ++i) {
            float4 v0 = *(const float4*)(xl + i*WW);
            float4 v1 = *(const float4*)(xl + i*WW + 4);
            s += v0.x+v0.y+v0.z+v0.w + v1.x+v1.y+v1.z+v1.w;
        }
    }
    s += __shfl_xor(s, 1);
    s += __shfl_xor(s, 2);

    __shared__ float meanc[CCH];
    __shared__ float logits[NE];
    if (part == 0) meanc[c] = s * (1.f/512.f);
    __syncthreads();
    if (t < NE) {
        float acc = rb[t];
        for (int cc = 0; cc < CCH; ++cc) acc += meanc[cc] * rw[t*CCH + cc];
        logits[t] = acc;
    }
    __syncthreads();
    if (t == 0) {
        float m0 = -1e30f; int i0 = 0;
        #pragma unroll
        for (int e = 0; e < NE; ++e) { float v = logits[e]; if (v > m0) { m0 = v; i0 = e; } }
        float m1 = -1e30f; int i1 = 0;
        #pragma unroll
        for (int e = 0; e < NE; ++e) { if (e != i0) { float v = logits[e]; if (v > m1) { m1 = v; i1 = e; } } }
        float dd = __expf(m1 - m0);
        float inv = 1.f / (1.f + dd);
        sel_idx[n*2]   = i0;  sel_idx[n*2+1] = i1;
        sel_w[n*2]     = inv; sel_w[n*2+1]   = dd * inv;
    }
}

// ---------------- New path: one block per patch, conv via MFMA over l-batch ----------------
__global__ __launch_bounds__(256)
void moe_mfma(const float* __restrict__ x,
              const float* __restrict__ ln_g,
              const float* __restrict__ ln_b,
              const float* __restrict__ pwin_b,
              const float* __restrict__ pwout_b,
              const unsigned short* __restrict__ w1t,
              const unsigned short* __restrict__ w2t,
              const float* __restrict__ w1sum,
              const unsigned short* __restrict__ mx,
              const int* __restrict__ sel_idx,
              const float* __restrict__ sel_w,
              float* __restrict__ out)
{
    __shared__ __align__(16) unsigned smem[20480];     // 80 KiB
    unsigned* Ydw = smem;                              // [0,16384) dwords: Y bf16 [8l][64s][64c] swz
    unsigned* G   = smem + 16384;                      // 2048 dwords used
    float* obuf   = (float*)(smem + 16384);            // 4096 dwords (aliases G)

    int n = blockIdx.x;
    int b = n / (NPH*NPW);
    int rem = n - b*(NPH*NPW);
    int ph = rem / NPW, pw = rem - ph*NPW;

    int t = threadIdx.x;
    int lane = t & 63;
    int q = __builtin_amdgcn_readfirstlane(t >> 6);
    int cbase = q*16;
    int laneM = lane & 31, hi = lane >> 5;
    int col16 = lane & 15, grp = lane >> 4;
    int i0 = lane >> 3, j0 = lane & 7;

    // zero-fill LDS (uninit-read insurance)
    {
        uint4 zz; zz.x = 0; zz.y = 0; zz.z = 0; zz.w = 0;
        uint4* zp = (uint4*)smem;
        #pragma unroll
        for (int i = 0; i < 20; ++i) zp[t + 256*i] = zz;
    }
    __syncthreads();

    size_t xpb = ((size_t)(b*CCH)*LL)*HWX + (size_t)(ph*PP)*WW + pw*PP;

    int e0 = __builtin_amdgcn_readfirstlane(sel_idx[n*2]);
    int e1 = __builtin_amdgcn_readfirstlane(sel_idx[n*2+1]);
    float w0 = sel_w[n*2], w1 = sel_w[n*2+1];

    int leff = lane & 7;
    size_t bloff = (size_t)leff*HWX + (size_t)grp*WW;
    bool wmask = col16 < 8;

    int dprime = 32*q + laneM;
    int borig  = (dprime & 1) ? 64 + (dprime >> 1) : (dprime >> 1);
    int cn     = 32*(q >> 1) + laneM;
    bool oddl  = (lane & 1) != 0;
    int kg     = 16*q + (laneM >> 1);
    int kdg    = kg >> 1, kbit = kg & 1;
    int srow_b = (oddl ? 32 : 0) + 4*hi;

    #pragma unroll 1
    for (int pass = 0; pass < 2; ++pass) {
        int e    = pass ? e1 : e0;
        float we = pass ? w1 : w0;

        __syncthreads();   // Y region free

        // ---- depthwise conv via MFMA (batched over l) + LN -> Ydw ----
        const unsigned short* mxe = mx + (((size_t)(e*CCH + cbase)) << 12);
        const float* xcb = x + xpb;
        #pragma unroll 2
        for (int m = 0; m < 16; ++m) {
            int c = cbase + m;
            const unsigned short* mxc = mxe + ((size_t)m << 12);
            const float* bp = xcb + (size_t)c*CSTRIDE + bloff;
            f32x4 acc[4];
            #pragma unroll
            for (int mt = 0; mt < 4; ++mt) { acc[mt][0]=0.f; acc[mt][1]=0.f; acc[mt][2]=0.f; acc[mt][3]=0.f; }
            #pragma unroll
            for (int ks = 0; ks < 2; ++ks) {
                float4 v0 = *(const float4*)(bp + ks*4*WW);
                float4 v1 = *(const float4*)(bp + ks*4*WW + 4);
                uint4 bu;
                bu.x = (unsigned)f2bf(v0.x) | ((unsigned)f2bf(v0.y) << 16);
                bu.y = (unsigned)f2bf(v0.z) | ((unsigned)f2bf(v0.w) << 16);
                bu.z = (unsigned)f2bf(v1.x) | ((unsigned)f2bf(v1.y) << 16);
                bu.w = (unsigned)f2bf(v1.z) | ((unsigned)f2bf(v1.w) << 16);
                bf16x8 bf = __builtin_bit_cast(bf16x8, bu);
                #pragma unroll
                for (int mt = 0; mt < 4; ++mt) {
                    uint4 au = *(const uint4*)(mxc + ((mt*2 + ks) << 9) + lane*8);
                    acc[mt] = __builtin_amdgcn_mfma_f32_16x16x32_bf16(
                        __builtin_bit_cast(bf16x8, au), bf, acc[mt], 0, 0, 0);
                }
            }
            // LN stats over the 64 spatial outputs of this (c, l): lane holds rows {16mt+4grp+r}
            float sum = 0.f, sq = 0.f;
            #pragma unroll
            for (int mt = 0; mt < 4; ++mt)
                #pragma unroll
                for (int r = 0; r < 4; ++r) { float v = acc[mt][r]; sum += v; sq = fmaf(v, v, sq); }
            sum += __shfl_xor(sum, 16); sum += __shfl_xor(sum, 32);
            sq  += __shfl_xor(sq, 16);  sq  += __shfl_xor(sq, 32);
            float mu  = sum * 0.015625f;
            float var = fmaxf(fmaf(sq, 0.015625f, -mu*mu), 0.f);
            float inv = rsqrtf(var + 1e-5f);
            float nmu = -mu * inv;
            if (wmask) {
                unsigned short* Yh = (unsigned short*)Ydw;
                #pragma unroll
                for (int mt = 0; mt < 4; ++mt)
                    #pragma unroll
                    for (int r = 0; r < 4; ++r) {
                        int s = 16*mt + 4*grp + r;
                        float yv = fmaf(acc[mt][r], inv, nmu);
                        int dwi = (c >> 1) ^ ((((s & 7) ^ leff)) << 2);
                        int half = (leff*8192 + s*128 + 4*dwi + 2*(c & 1)) >> 1;
                        Yh[half] = f2bf(yv);
                    }
            }
        }

        // ---- per-pass GEMM constants ----
        const unsigned short* w1e = w1t + ((size_t)e << 13);
        const unsigned short* w2e = w2t + ((size_t)e << 12);
        uint4 b1f[4], b2f[4];
        #pragma unroll
        for (int ks = 0; ks < 4; ++ks)
            b1f[ks] = *(const uint4*)(w1e + dprime*64 + 16*ks + 8*hi);
        #pragma unroll
        for (int ks = 0; ks < 4; ++ks)
            b2f[ks] = *(const uint4*)(w2e + cn*64 + 16*ks + 8*hi);
        float bias1 = pwin_b[e*128 + borig];
        float bias2 = pwout_b[e*64 + cn];
        float w1s   = w1sum[e*128 + dprime];
        float g0v[16], a0c[16], g1v[16], a1c[16];
        #pragma unroll
        for (int r = 0; r < 16; ++r) {
            int sr = (r & 3) + 8*(r >> 2) + 4*hi;
            g0v[r] = ln_g[e*64 + sr];
            a0c[r] = fmaf(ln_b[e*64 + sr], w1s, bias1);
            g1v[r] = ln_g[e*64 + 32 + sr];
            a1c[r] = fmaf(ln_b[e*64 + 32 + sr], w1s, bias1);
        }

        __syncthreads();   // Ydw complete

        #pragma unroll 1
        for (int l = 0; l < 8; ++l) {
            int lbase = l*2048;
            int lsw = l << 2;
            // ---- GEMM1 ----
            f32x16 acc0, acc1;
            #pragma unroll
            for (int i = 0; i < 16; ++i) { acc0[i] = 0.f; acc1[i] = 0.f; }
            #pragma unroll
            for (int ks = 0; ks < 4; ++ks) {
                int kd = 8*ks + 4*hi;
                int sA = laneM, sB = 32 + laneM;
                uint4 a0u = *(const uint4*)&Ydw[lbase + sA*32 + ((kd ^ ((sA & 7) << 2)) ^ lsw)];
                uint4 a1u = *(const uint4*)&Ydw[lbase + sB*32 + ((kd ^ ((sB & 7) << 2)) ^ lsw)];
                bf16x8 bv = __builtin_bit_cast(bf16x8, b1f[ks]);
                acc0 = __builtin_amdgcn_mfma_f32_32x32x16_bf16(__builtin_bit_cast(bf16x8, a0u), bv, acc0, 0, 0, 0);
                acc1 = __builtin_amdgcn_mfma_f32_32x32x16_bf16(__builtin_bit_cast(bf16x8, a1u), bv, acc1, 0, 0, 0);
            }
            __syncthreads();   // prev-l obuf reads done
            // ---- gate (folded LN affine) ----
            #pragma unroll
            for (int r = 0; r < 16; ++r) {
                float h0 = fmaf(acc0[r], g0v[r], a0c[r]);
                float h1 = fmaf(acc1[r], g1v[r], a1c[r]);
                float p0 = dpp_xor1(h0);
                float p1 = dpp_xor1(h1);
                float A0 = oddl ? p0 : h0, G0 = oddl ? h0 : p0;
                float A1 = oddl ? p1 : h1, G1 = oddl ? h1 : p1;
                float ga = __fdividef(A0, 1.f + __expf(-A0)) * G0;
                float gb = __fdividef(A1, 1.f + __expf(-A1)) * G1;
                float val = oddl ? gb : ga;
                int srow = srow_b + (r & 3) + 8*(r >> 2);
                int gd = srow*32 + (kdg ^ ((srow & 7) << 2));
                ((unsigned short*)G)[gd*2 + kbit] = f2bf(val);
            }
            __syncthreads();   // G ready
            // ---- GEMM2 ----
            f32x16 gacc;
            #pragma unroll
            for (int i = 0; i < 16; ++i) gacc[i] = 0.f;
            #pragma unroll
            for (int ks = 0; ks < 4; ++ks) {
                int sG = 32*(q & 1) + laneM;
                int kd = 8*ks + 4*hi;
                uint4 ag = *(const uint4*)&G[sG*32 + (kd ^ ((sG & 7) << 2))];
                gacc = __builtin_amdgcn_mfma_f32_32x32x16_bf16(
                    __builtin_bit_cast(bf16x8, ag), __builtin_bit_cast(bf16x8, b2f[ks]), gacc, 0, 0, 0);
            }
            __syncthreads();   // all G reads done (obuf aliases G)
            // ---- obuf transpose write ----
            {
                int s_base = 32*(q & 1) + 4*hi;
                #pragma unroll
                for (int r = 0; r < 16; ++r) {
                    int s = s_base + (r & 3) + 8*(r >> 2);
                    obuf[cn*64 + (s ^ (cn & 31))] = we * (gacc[r] + bias2);
                }
            }
            __syncthreads();   // obuf ready
            // ---- global store ----
            size_t gl = xpb + (size_t)l*HWX + (size_t)i0*WW + j0;
            #pragma unroll
            for (int m2 = 0; m2 < 16; ++m2) {
                int c = cbase + m2;
                float v = obuf[c*64 + (lane ^ (c & 31))];
                size_t ga = gl + (size_t)c*CSTRIDE;
                if (pass == 0) out[ga] = v + x[ga];
                else           out[ga] += v;
            }
        }
    }
}

// ---------------- Fallback: verified round-3 kernel (one block per (patch,l)) ----------------
__global__ __launch_bounds__(256, 4)
void moe_r3(const float* __restrict__ x,
            const float* __restrict__ dw_w,
            const float* __restrict__ dw_b,
            const float* __restrict__ ln_g,
            const float* __restrict__ ln_b,
            const float* __restrict__ pwin_b,
            const float* __restrict__ pwout_b,
            const unsigned short* __restrict__ w1t,
            const unsigned short* __restrict__ w2t,
            const int* __restrict__ sel_idx,
            const float* __restrict__ sel_w,
            float* __restrict__ out)
{
    __shared__ __align__(16) unsigned smem[8192];
    float* xin   = (float*)smem;
    unsigned* Y  = smem + 4096;
    unsigned* G  = smem + 6144;
    float* obuf  = (float*)(smem + 4096);

    int bid = blockIdx.x;
    int n = bid >> 3;
    int l = bid & 7;
    int b = n / (NPH*NPW);
    int rem = n - b*(NPH*NPW);
    int ph = rem / NPW, pw = rem - ph*NPW;

    int t = threadIdx.x;
    int lane = t & 63;
    int q = __builtin_amdgcn_readfirstlane(t >> 6);
    int cbase = q*16;
    int i0 = lane >> 3, j0 = lane & 7;
    int laneM = lane & 31, hi = lane >> 5;

    bool l1ok = j0 < 7, l2ok = j0 < 6, l3ok = j0 < 5;
    bool r1ok = j0 > 0, r2ok = j0 > 1, r3ok = j0 > 2;
    bool u1ok = i0 < 7, u2ok = i0 < 6, u3ok = i0 < 5;
    bool d1ok = i0 > 0, d2ok = i0 > 1, d3ok = i0 > 2;
    int aup1 = ((lane + 8)  & 63) << 2, aup2 = ((lane + 16) & 63) << 2, aup3 = ((lane + 24) & 63) << 2;
    int adn1 = ((lane - 8)  & 63) << 2, adn2 = ((lane - 16) & 63) << 2, adn3 = ((lane - 24) & 63) << 2;

    size_t pbase = ((size_t)(b*CCH)*LL + l)*HWX + (size_t)(ph*PP)*WW + pw*PP;
    for (int idx4 = t; idx4 < 1024; idx4 += 256) {
        int c = idx4 >> 4, r = idx4 & 15, ii = r >> 1, jj = (r & 1)*4;
        float4 v = *(const float4*)(x + pbase + (size_t)c*CSTRIDE + ii*WW + jj);
        *(float4*)(xin + c*64 + ii*8 + jj) = v;
    }

    int e0 = __builtin_amdgcn_readfirstlane(sel_idx[n*2]);
    int e1 = __builtin_amdgcn_readfirstlane(sel_idx[n*2+1]);
    float w0 = sel_w[n*2], w1 = sel_w[n*2+1];

    f32x16 out_acc;
    #pragma unroll
    for (int i = 0; i < 16; ++i) out_acc[i] = 0.f;

    int dprime = 32*q + laneM;
    int borig  = (dprime & 1) ? 64 + (dprime >> 1) : (dprime >> 1);
    int cn     = 32*(q >> 1) + laneM;
    int xv     = (lane & 7) << 2;
    bool oddl  = (lane & 1) != 0;
    int kg     = 16*q + (laneM >> 1);
    int kdg    = kg >> 1, kbit = kg & 1;
    int srow_b = (oddl ? 32 : 0) + 4*hi;

    #pragma unroll 1
    for (int pass = 0; pass < 2; ++pass) {
        int e = pass ? e1 : e0;
        float we = pass ? w1 : w0;

        const unsigned short* w1e = w1t + ((size_t)e << 13);
        const unsigned short* w2e = w2t + ((size_t)e << 12);
        uint4 b1f[4], b2f[4];
        #pragma unroll
        for (int ks = 0; ks < 4; ++ks)
            b1f[ks] = *(const uint4*)(w1e + (32*q + laneM)*64 + 16*ks + 8*hi);
        #pragma unroll
        for (int ks = 0; ks < 4; ++ks)
            b2f[ks] = *(const uint4*)(w2e + cn*64 + 16*ks + 8*hi);
        float bias1 = pwin_b[e*128 + borig];
        float bias2 = pwout_b[e*64 + cn];
        float lng = ln_g[e*64 + lane];
        float lnb = ln_b[e*64 + lane];

        __syncthreads();

        unsigned ypack[8];
        #pragma unroll
        for (int i = 0; i < 8; ++i) ypack[i] = 0u;

        #pragma unroll
        for (int m = 0; m < 16; ++m) {
            int c = cbase + m;
            const float* wr = dw_w + ((size_t)e*CCH + c)*49;
            float v = xin[c*64 + lane];
            float xl1 = dpp0<0x101>(v); xl1 = l1ok ? xl1 : 0.f;
            float xl2 = dpp0<0x102>(v); xl2 = l2ok ? xl2 : 0.f;
            float xl3 = dpp0<0x103>(v); xl3 = l3ok ? xl3 : 0.f;
            float xr1 = dpp0<0x111>(v); xr1 = r1ok ? xr1 : 0.f;
            float xr2 = dpp0<0x112>(v); xr2 = r2ok ? xr2 : 0.f;
            float xr3 = dpp0<0x113>(v); xr3 = r3ok ? xr3 : 0.f;
            float S0,S1,S2,S3,S4,S5,S6;
            #define ROW1D(SS, di) { const float* w7 = wr + (di)*7;            \
                float a = xr3 * w7[0];  a = fmaf(xr2, w7[1], a);              \
                a = fmaf(xr1, w7[2], a); a = fmaf(v,  w7[3], a);              \
                a = fmaf(xl1, w7[4], a); a = fmaf(xl2, w7[5], a);             \
                a = fmaf(xl3, w7[6], a); SS = a; }
            ROW1D(S0,0) ROW1D(S1,1) ROW1D(S2,2) ROW1D(S3,3) ROW1D(S4,4) ROW1D(S5,5) ROW1D(S6,6)
            #undef ROW1D
            float o = S3 + dw_b[(size_t)e*CCH + c];
            float p;
            p = bperm(aup1, S4); o += u1ok ? p : 0.f;
            p = bperm(aup2, S5); o += u2ok ? p : 0.f;
            p = bperm(aup3, S6); o += u3ok ? p : 0.f;
            p = bperm(adn1, S2); o += d1ok ? p : 0.f;
            p = bperm(adn2, S1); o += d2ok ? p : 0.f;
            p = bperm(adn3, S0); o += d3ok ? p : 0.f;
            float ssum = wsum64(o);
            float ssq  = wsum64(o*o);
            float mu  = ssum * 0.015625f;
            float var = ssq  * 0.015625f - mu*mu;
            float inv = rsqrtf(var + 1e-5f);
            float yv  = (o - mu) * inv * lng + lnb;
            ypack[m >> 1] |= ((unsigned)f2bf(yv)) << ((m & 1) * 16);
        }
        {
            uint4 v0; v0.x = ypack[0]; v0.y = ypack[1]; v0.z = ypack[2]; v0.w = ypack[3];
            uint4 v1; v1.x = ypack[4]; v1.y = ypack[5]; v1.z = ypack[6]; v1.w = ypack[7];
            *(uint4*)&Y[lane*32 + ((8*q + 0) ^ xv)] = v0;
            *(uint4*)&Y[lane*32 + ((8*q + 4) ^ xv)] = v1;
        }
        __syncthreads();

        f32x16 acc0, acc1;
        #pragma unroll
        for (int i = 0; i < 16; ++i) { acc0[i] = 0.f; acc1[i] = 0.f; }
        #pragma unroll
        for (int ks = 0; ks < 4; ++ks) {
            int kd = 8*ks + 4*hi;
            int s0 = laneM, s1 = 32 + laneM;
            uint4 a0 = *(const uint4*)&Y[s0*32 + (kd ^ ((s0 & 7) << 2))];
            uint4 a1 = *(const uint4*)&Y[s1*32 + (kd ^ ((s1 & 7) << 2))];
            bf16x8 bv = __builtin_bit_cast(bf16x8, b1f[ks]);
            acc0 = __builtin_amdgcn_mfma_f32_32x32x16_bf16(__builtin_bit_cast(bf16x8, a0), bv, acc0, 0, 0, 0);
            acc1 = __builtin_amdgcn_mfma_f32_32x32x16_bf16(__builtin_bit_cast(bf16x8, a1), bv, acc1, 0, 0, 0);
        }
        #pragma unroll
        for (int r = 0; r < 16; ++r) {
            float h0 = acc0[r] + bias1;
            float h1 = acc1[r] + bias1;
            float p0 = dpp_xor1(h0);
            float p1 = dpp_xor1(h1);
            float a0 = oddl ? p0 : h0, g0 = oddl ? h0 : p0;
            float a1 = oddl ? p1 : h1, g1 = oddl ? h1 : p1;
            float ga = __fdividef(a0, 1.f + __expf(-a0)) * g0;
            float gb = __fdividef(a1, 1.f + __expf(-a1)) * g1;
            float val = oddl ? gb : ga;
            int srow = srow_b + (r & 3) + 8*(r >> 2);
            int gd = srow*32 + (kdg ^ ((srow & 7) << 2));
            ((unsigned short*)G)[gd*2 + kbit] = f2bf(val);
        }
        __syncthreads();

        f32x16 gacc;
        #pragma unroll
        for (int i = 0; i < 16; ++i) gacc[i] = 0.f;
        #pragma unroll
        for (int ks = 0; ks < 4; ++ks) {
            int s = 32*(q & 1) + laneM;
            int kd = 8*ks + 4*hi;
            uint4 ag = *(const uint4*)&G[s*32 + (kd ^ ((s & 7) << 2))];
            gacc = __builtin_amdgcn_mfma_f32_32x32x16_bf16(
                __builtin_bit_cast(bf16x8, ag), __builtin_bit_cast(bf16x8, b2f[ks]), gacc, 0, 0, 0);
        }
        #pragma unroll
        for (int r = 0; r < 16; ++r) out_acc[r] += we * (gacc[r] + bias2);
    }

    __syncthreads();
    {
        int s_base = 32*(q & 1) + 4*hi;
        #pragma unroll
        for (int r = 0; r < 16; ++r) {
            int s = s_base + (r & 3) + 8*(r >> 2);
            obuf[cn*64 + (s ^ (cn & 31))] = out_acc[r];
        }
    }
    __syncthreads();
    #pragma unroll
    for (int m = 0; m < 16; ++m) {
        int c = cbase + m;
        float val = obuf[c*64 + (lane ^ (c & 31))] + xin[c*64 + lane];
        out[pbase + (size_t)c*CSTRIDE + i0*WW + j0] = val;
    }
}

extern "C" void kernel_launch(void* const* d_in, const int* in_sizes, int n_in,
                              void* d_out, int out_size, void* d_ws, size_t ws_size,
                              hipStream_t stream) {
    const float* x        = (const float*)d_in[0];
    const float* router_w = (const float*)d_in[1];
    const float* router_b = (const float*)d_in[2];
    const float* dw_w     = (const float*)d_in[3];
    const float* dw_b     = (const float*)d_in[4];
    const float* ln_g     = (const float*)d_in[5];
    const float* ln_b     = (const float*)d_in[6];
    const float* pwin_w   = (const float*)d_in[7];
    const float* pwin_b   = (const float*)d_in[8];
    const float* pwout_w  = (const float*)d_in[9];
    const float* pwout_b  = (const float*)d_in[10];
    float* out = (float*)d_out;

    char* ws = (char*)d_ws;
    int*            sel_idx = (int*)ws;                        // [0, 6400)
    float*          sel_w   = (float*)(ws + 6400);             // [6400, 12800)
    unsigned short* w1t     = (unsigned short*)(ws + 12800);   // 131072 B
    unsigned short* w2t     = (unsigned short*)(ws + 143872);  // 65536 B
    float*          w1sum   = (float*)(ws + 209408);           // 4096 B
    unsigned short* mx      = (unsigned short*)(ws + 213504);  // 4 MiB -> ends 4407808

    const size_t NEED_FULL = 4407808;
    int full = (ws_size >= NEED_FULL) ? 1 : 0;

    prep_kernel<<<full ? 8192 : 256, 256, 0, stream>>>(pwin_w, pwout_w, dw_w,
                                                       w1t, w2t, w1sum, mx, full);
    router_kernel<<<NPAT, 256, 0, stream>>>(x, router_w, router_b, sel_idx, sel_w);
    if (full) {
        moe_mfma<<<NPAT, 256, 0, stream>>>(x, ln_g, ln_b, pwin_b, pwout_b,
                                           w1t, w2t, w1sum, mx, sel_idx, sel_w, out);
    } else {
        moe_r3<<<NPAT*LL, 256, 0, stream>>>(x, dw_w, dw_b, ln_g, ln_b,
                                            pwin_b, pwout_b, w1t, w2t,
                                            sel_idx, sel_w, out);
    }
}